// Round 2
// baseline (2421.452 us; speedup 1.0000x reference)
//
#include <hip/hip_runtime.h>

#define DD 64

// One wave (64 lanes) per edge; lane = feature dim.
// sum[dst*64+lane] += emb[src*64+lane] * weight[type*64+lane]  (f32 atomics)
// cnt[dst] += 1 (lane 0)
__global__ void scatter_kernel(const float* __restrict__ emb,
                               const float* __restrict__ weight,
                               const int* __restrict__ dst_idx,
                               const int* __restrict__ src_idx,
                               const int* __restrict__ etype,   // nullptr -> type 0
                               float* __restrict__ sum,
                               float* __restrict__ cnt,
                               int n_edges) {
    int e = blockIdx.x * (blockDim.x >> 6) + (threadIdx.x >> 6);
    int lane = threadIdx.x & 63;
    if (e >= n_edges) return;
    int dst = dst_idx[e];
    int src = src_idx[e];
    int t = etype ? etype[e] : 0;
    float v = emb[(size_t)src * DD + lane] * weight[t * DD + lane];
    atomicAdd(&sum[(size_t)dst * DD + lane], v);
    if (lane == 0) atomicAdd(&cnt[dst], 1.0f);
}

// out = sig(a@gA.T + b@gB.T) * a + (1-sig) * b, where a=asum/max(acnt,1), b=bsum/max(bcnt,1)
// One wave per row. Gates staged transposed in LDS: G[k][d] = g[d*64+k] so that
// lane d reads G[k][d] stride-1 (2 lanes/bank -> conflict-free).
__global__ void gate_fuse_kernel(const float* __restrict__ asum, const float* __restrict__ acnt,
                                 const float* __restrict__ bsum, const float* __restrict__ bcnt,
                                 const float* __restrict__ gA,
                                 const float* __restrict__ gB,
                                 float* __restrict__ out,
                                 int n_rows) {
    __shared__ float GA[DD][DD];   // GA[k][d] = gA[d][k]
    __shared__ float GB[DD][DD];
    for (int i = threadIdx.x; i < DD * DD; i += blockDim.x) {
        int d = i >> 6, k = i & 63;
        GA[k][d] = gA[i];
        GB[k][d] = gB[i];
    }
    __syncthreads();
    int row = blockIdx.x * (blockDim.x >> 6) + (threadIdx.x >> 6);
    int lane = threadIdx.x & 63;
    if (row >= n_rows) return;
    float ca = acnt[row]; ca = ca < 1.f ? 1.f : ca;
    float cb = bcnt[row]; cb = cb < 1.f ? 1.f : cb;
    float a = asum[(size_t)row * DD + lane] / ca;
    float b = bsum[(size_t)row * DD + lane] / cb;
    float z = 0.f;
    #pragma unroll
    for (int k = 0; k < DD; ++k) {
        float ak = __shfl(a, k, 64);
        float bk = __shfl(b, k, 64);
        z += ak * GA[k][lane] + bk * GB[k][lane];
    }
    float g = 1.f / (1.f + expf(-z));
    float o = g * a + (1.f - g) * b;
    out[(size_t)row * DD + lane] = o;
}

// out[row] = sum[row]/max(cnt[row],1) for row in [row_start, row_end)
__global__ void mean_tail_kernel(const float* __restrict__ sum, const float* __restrict__ cnt,
                                 float* __restrict__ out,
                                 int row_start, int row_end) {
    int idx = blockIdx.x * blockDim.x + threadIdx.x;
    int row = row_start + (idx >> 6);
    if (row >= row_end) return;
    int lane = idx & 63;
    float c = cnt[row]; c = c < 1.f ? 1.f : c;
    out[(size_t)row * DD + lane] = sum[(size_t)row * DD + lane] / c;
}

extern "C" void kernel_launch(void* const* d_in, const int* in_sizes, int n_in,
                              void* d_out, int out_size, void* d_ws, size_t ws_size,
                              hipStream_t stream) {
    const float* entity_emb = (const float*)d_in[0];
    const float* user_emb   = (const float*)d_in[1];
    const float* weight     = (const float*)d_in[2];
    const float* g1         = (const float*)d_in[3];
    const float* g2         = (const float*)d_in[4];
    const float* g3         = (const float*)d_in[5];
    const int* edge_index  = (const int*)d_in[6];   // (2, E): row0=head(dst), row1=tail(src)
    const int* edge_type   = (const int*)d_in[7];
    const int* uedge_index = (const int*)d_in[8];   // (2, UE)
    const int* uedge_type  = (const int*)d_in[9];
    const int* mat_row     = (const int*)d_in[10];  // users
    const int* mat_col     = (const int*)d_in[11];  // items

    const int n_entities   = in_sizes[0] / DD;  // 180000
    const int n_user_nodes = in_sizes[1] / DD;  // 150000
    const int n_edges      = in_sizes[7];       // 1500000
    const int n_uedges     = in_sizes[9];       // 1000000
    const int n_mat        = in_sizes[10];      // 1500000
    const int n_items      = 50000;
    const int n_users      = 100000;

    // f32 workspace layout
    float* ws = (float*)d_ws;
    size_t off = 0;
    float* esum  = ws + off; off += (size_t)n_entities * DD;
    float* asum  = ws + off; off += (size_t)n_user_nodes * DD;
    float* iusum = ws + off; off += (size_t)n_items * DD;
    float* uisum = ws + off; off += (size_t)n_users * DD;
    float* ecnt  = ws + off; off += n_entities;
    float* acnt  = ws + off; off += n_user_nodes;
    float* iucnt = ws + off; off += n_items;
    float* uicnt = ws + off; off += n_users;
    hipMemsetAsync(d_ws, 0, off * sizeof(float), stream);

    dim3 blk(256);  // 4 waves/block

    // entity_agg = scatter_mean(entity_emb[tail]*weight[edge_type], head)
    scatter_kernel<<<(n_edges + 3) / 4, blk, 0, stream>>>(
        entity_emb, weight, edge_index, edge_index + n_edges, edge_type,
        esum, ecnt, n_edges);
    // attribute_agg = scatter_mean(user_emb[utail]*weight[user_edge_type], uhead)
    scatter_kernel<<<(n_uedges + 3) / 4, blk, 0, stream>>>(
        user_emb, weight, uedge_index, uedge_index + n_uedges, uedge_type,
        asum, acnt, n_uedges);
    // i_u_agg = scatter_mean(user_emb[mat_row]*weight[0], mat_col, N_ITEMS)
    scatter_kernel<<<(n_mat + 3) / 4, blk, 0, stream>>>(
        user_emb, weight, mat_col, mat_row, nullptr,
        iusum, iucnt, n_mat);
    // u_i_agg = scatter_mean(entity_emb[mat_col]*weight[0], mat_row, N_USERS)
    scatter_kernel<<<(n_mat + 3) / 4, blk, 0, stream>>>(
        entity_emb, weight, mat_row, mat_col, nullptr,
        uisum, uicnt, n_mat);

    float* out      = (float*)d_out;
    float* user_out = out + (size_t)n_entities * DD;

    // items: gi = sig(item_kg@g1.T + i_u@g2.T); out = gi*item_kg + (1-gi)*i_u
    gate_fuse_kernel<<<(n_items + 3) / 4, blk, 0, stream>>>(
        esum, ecnt, iusum, iucnt, g1, g2, out, n_items);
    // entity tail rows [n_items, n_entities)
    {
        long long threads = (long long)(n_entities - n_items) * DD;
        mean_tail_kernel<<<(unsigned)((threads + 255) / 256), blk, 0, stream>>>(
            esum, ecnt, out, n_items, n_entities);
    }
    // users: hi = sig(u_i@g2.T + ukg@g3.T); out = hi*ukg + (1-hi)*u_i
    //   a = ukg (asum/acnt) paired with g3, b = u_i (uisum/uicnt) paired with g2
    gate_fuse_kernel<<<(n_users + 3) / 4, blk, 0, stream>>>(
        asum, acnt, uisum, uicnt, g3, g2, user_out, n_users);
    // user tail rows [n_users, n_user_nodes)
    {
        long long threads = (long long)(n_user_nodes - n_users) * DD;
        mean_tail_kernel<<<(unsigned)((threads + 255) / 256), blk, 0, stream>>>(
            asum, acnt, user_out, n_users, n_user_nodes);
    }
}